// Round 5
// baseline (579.653 us; speedup 1.0000x reference)
//
#include <hip/hip_runtime.h>

typedef unsigned short ushort_t;
typedef unsigned int uint_t;
typedef __attribute__((ext_vector_type(8))) short s8v;     // 8 x bf16 (4 VGPRs)
typedef __attribute__((ext_vector_type(4))) float f4v;     // 4 x fp32

// Problem constants (fixed by the reference)
#define NS0 100000
#define ND0 20000
#define ND1 4000
#define E0  640000
#define E1  128000
#define F   512     // IN_F == HID_F
#define OF  256
#define NCNT (NS0 + ND0 + ND0 + ND1)   // 144000
#define SB  96                          // bucket stride; Poisson(32) max deg ~57, P(>96)~1e-16

#define WBLK ((F * F + F * OF) / 256)      // 1536

__device__ __forceinline__ ushort_t f2b(float f) {
    uint_t u = __float_as_uint(f);
    uint_t r = (u + 0x7fffu + ((u >> 16) & 1u)) >> 16;
    return (ushort_t)r;
}
__device__ __forceinline__ float b2f_lo(uint_t u) { return __uint_as_float(u << 16); }
__device__ __forceinline__ float b2f_hi(uint_t u) { return __uint_as_float(u & 0xffff0000u); }

// Front kernel: bucket-fill (blocks [0,750)) + W transpose-convert. The x->bf16
// streaming pass is GONE (R4 post-mortem: prep was pinned at 138us across 1- and
// 4-load variants — the 307MB x/xb stream was structural overhead; agg_l1 now
// gathers f32 x directly out of L3 instead).
__global__ __launch_bounds__(256) void prep(const int* __restrict__ src0, const int* __restrict__ dst0,
                                            const int* __restrict__ src1, const int* __restrict__ dst1,
                                            int* __restrict__ cntOut0, int* __restrict__ cntIn0,
                                            int* __restrict__ cntOut1, int* __restrict__ cntIn1,
                                            int* __restrict__ es0, int* __restrict__ es1,
                                            const float* __restrict__ W1, const float* __restrict__ W2,
                                            ushort_t* __restrict__ wt1, ushort_t* __restrict__ wt2) {
    int b = blockIdx.x;
    if (b < 625) {
        // layer-0 edges: E0 = 640000 = 625*1024; 4 edges/thread via int4 for atomic MLP
        int e = (b * 256 + threadIdx.x) * 4;
        int4 s = *(const int4*)(src0 + e);
        int4 d = *(const int4*)(dst0 + e);
        atomicAdd(&cntOut0[s.x], 1);
        atomicAdd(&cntOut0[s.y], 1);
        atomicAdd(&cntOut0[s.z], 1);
        atomicAdd(&cntOut0[s.w], 1);
        int p0 = atomicAdd(&cntIn0[d.x], 1);
        int p1 = atomicAdd(&cntIn0[d.y], 1);
        int p2 = atomicAdd(&cntIn0[d.z], 1);
        int p3 = atomicAdd(&cntIn0[d.w], 1);
        es0[d.x * SB + min(p0, SB - 1)] = s.x;
        es0[d.y * SB + min(p1, SB - 1)] = s.y;
        es0[d.z * SB + min(p2, SB - 1)] = s.z;
        es0[d.w * SB + min(p3, SB - 1)] = s.w;
        return;
    }
    if (b < 750) {
        // layer-1 edges: E1 = 128000 = 125*1024
        int e = ((b - 625) * 256 + threadIdx.x) * 4;
        int4 s = *(const int4*)(src1 + e);
        int4 d = *(const int4*)(dst1 + e);
        atomicAdd(&cntOut1[s.x], 1);
        atomicAdd(&cntOut1[s.y], 1);
        atomicAdd(&cntOut1[s.z], 1);
        atomicAdd(&cntOut1[s.w], 1);
        int p0 = atomicAdd(&cntIn1[d.x], 1);
        int p1 = atomicAdd(&cntIn1[d.y], 1);
        int p2 = atomicAdd(&cntIn1[d.z], 1);
        int p3 = atomicAdd(&cntIn1[d.w], 1);
        es1[d.x * SB + min(p0, SB - 1)] = s.x;
        es1[d.y * SB + min(p1, SB - 1)] = s.y;
        es1[d.z * SB + min(p2, SB - 1)] = s.z;
        es1[d.w * SB + min(p3, SB - 1)] = s.w;
        return;
    }
    int i = (b - 750) * 256 + threadIdx.x;
    if (i < F * F) {
        int k = i >> 9, n = i & (F - 1);
        wt1[n * F + k] = f2b(W1[i]);
    } else {
        int j = i - F * F;
        int k = j >> 8, n = j & (OF - 1);
        wt2[n * F + k] = f2b(W2[j]);
    }
}

__device__ __forceinline__ void add8(float* acc, uint4 u) {
    acc[0] += b2f_lo(u.x); acc[1] += b2f_hi(u.x);
    acc[2] += b2f_lo(u.y); acc[3] += b2f_hi(u.y);
    acc[4] += b2f_lo(u.z); acc[5] += b2f_hi(u.z);
    acc[6] += b2f_lo(u.w); acc[7] += b2f_hi(u.w);
}

// L1 aggregation, f32-direct: one wave per dst row; gathers 2KB f32 rows of x
// straight from L3 (x 205MB < 256MB L3; re-read factor ~6.4 is absorbed; first
// touch is the one unavoidable HBM read of x). Per-edge out-degree scale in f32.
// 2-bank ping/pong pipeline with STATICALLY NAMED banks and duplicated consume
// bodies (rule #20: runtime-indexed banks spill to scratch — R3: 588MB scratch,
// 265us). 4 edges/chunk x 2 f4v loads = 8 gathers in flight per bank.
__global__ __launch_bounds__(256) void agg_l1(const float* __restrict__ X, const int* __restrict__ es,
                                              const int* __restrict__ cntIn, const int* __restrict__ cntOut,
                                              ushort_t* __restrict__ out, int ndst) {
    int d = __builtin_amdgcn_readfirstlane(blockIdx.x * 4 + (threadIdx.x >> 6));
    if (d >= ndst) return;
    int lane = threadIdx.x & 63;
    int n = min(cntIn[d], SB);
    const int* ed = es + (size_t)d * SB;
    const f4v* Xv = (const f4v*)X;     // row stride = 128 f4v; lane covers cols [lane*4, 256+lane*4]
    f4v accA = {0.f, 0.f, 0.f, 0.f};
    f4v accB = {0.f, 0.f, 0.f, 0.f};
    int c = n >> 2;           // full 4-chunks
    int i = c << 2;           // tail start
    if (c > 0) {
        int idP[4], idQ[4];
        f4v aP[4], bP[4], aQ[4], bQ[4];
        int cvP[4], cvQ[4];
        #pragma unroll
        for (int j = 0; j < 4; ++j) idP[j] = ed[j];
        #pragma unroll
        for (int j = 0; j < 4; ++j) {
            aP[j] = Xv[(size_t)idP[j] * 128 + lane];
            bP[j] = Xv[(size_t)idP[j] * 128 + 64 + lane];
        }
        #pragma unroll
        for (int j = 0; j < 4; ++j) cvP[j] = cntOut[idP[j]];
        if (c > 1) {
            #pragma unroll
            for (int j = 0; j < 4; ++j) idQ[j] = ed[4 + j];
        }
        int k = 0;
        while (true) {
            // P in flight for chunk k; idQ holds ids for k+1 (if any)
            if (k + 1 < c) {
                #pragma unroll
                for (int j = 0; j < 4; ++j) {
                    aQ[j] = Xv[(size_t)idQ[j] * 128 + lane];
                    bQ[j] = Xv[(size_t)idQ[j] * 128 + 64 + lane];
                }
                #pragma unroll
                for (int j = 0; j < 4; ++j) cvQ[j] = cntOut[idQ[j]];
                if (k + 2 < c) {
                    #pragma unroll
                    for (int j = 0; j < 4; ++j) idP[j] = ed[(k + 2) * 4 + j];
                }
            }
            #pragma unroll
            for (int j = 0; j < 4; ++j) {
                float sc = rsqrtf(fmaxf((float)cvP[j], 1.0f));
                accA += aP[j] * sc;
                accB += bP[j] * sc;
            }
            ++k;
            if (k >= c) break;
            // Q in flight for chunk k; idP holds ids for k+1 (if any)
            if (k + 1 < c) {
                #pragma unroll
                for (int j = 0; j < 4; ++j) {
                    aP[j] = Xv[(size_t)idP[j] * 128 + lane];
                    bP[j] = Xv[(size_t)idP[j] * 128 + 64 + lane];
                }
                #pragma unroll
                for (int j = 0; j < 4; ++j) cvP[j] = cntOut[idP[j]];
                if (k + 2 < c) {
                    #pragma unroll
                    for (int j = 0; j < 4; ++j) idQ[j] = ed[(k + 2) * 4 + j];
                }
            }
            #pragma unroll
            for (int j = 0; j < 4; ++j) {
                float sc = rsqrtf(fmaxf((float)cvQ[j], 1.0f));
                accA += aQ[j] * sc;
                accB += bQ[j] * sc;
            }
            ++k;
            if (k >= c) break;
        }
    }
    for (; i < n; ++i) {
        int s = ed[i];
        float sc = rsqrtf(fmaxf((float)cntOut[s], 1.0f));
        accA += Xv[(size_t)s * 128 + lane] * sc;
        accB += Xv[(size_t)s * 128 + 64 + lane] * sc;
    }
    float sc = rsqrtf(fmaxf((float)n, 1.0f));
    accA *= sc;
    accB *= sc;
    // out row = 512 bf16 = 128 uint2; lane's cols: [lane*4..+3] and [256+lane*4..+3]
    uint2 oA, oB;
    oA.x = (uint_t)f2b(accA.x) | ((uint_t)f2b(accA.y) << 16);
    oA.y = (uint_t)f2b(accA.z) | ((uint_t)f2b(accA.w) << 16);
    oB.x = (uint_t)f2b(accB.x) | ((uint_t)f2b(accB.y) << 16);
    oB.y = (uint_t)f2b(accB.z) | ((uint_t)f2b(accB.w) << 16);
    uint2* op = (uint2*)out;
    op[(size_t)d * 128 + lane] = oA;
    op[(size_t)d * 128 + 64 + lane] = oB;
}

// L2 aggregation: h is already out-degree-pre-scaled by gemm1's epilogue, so
// plain sum then in-degree scale. Statically-named 2-bank pipeline (bf16 rows).
__global__ __launch_bounds__(256) void agg_l2(const ushort_t* __restrict__ X, const int* __restrict__ es,
                                              const int* __restrict__ cntIn, ushort_t* __restrict__ out,
                                              int ndst) {
    int d = __builtin_amdgcn_readfirstlane(blockIdx.x * 4 + (threadIdx.x >> 6));
    if (d >= ndst) return;
    int lane = threadIdx.x & 63;
    int n = min(cntIn[d], SB);
    const int* ed = es + (size_t)d * SB;
    const uint4* Xv = (const uint4*)X;
    float acc[8] = {0.f, 0.f, 0.f, 0.f, 0.f, 0.f, 0.f, 0.f};
    int c = n >> 3;
    int i = c << 3;
    if (c > 0) {
        int idP[8], idQ[8];
        uint4 uP[8], uQ[8];
        #pragma unroll
        for (int j = 0; j < 8; ++j) idP[j] = ed[j];
        #pragma unroll
        for (int j = 0; j < 8; ++j) uP[j] = Xv[(size_t)idP[j] * 64 + lane];
        if (c > 1) {
            #pragma unroll
            for (int j = 0; j < 8; ++j) idQ[j] = ed[8 + j];
        }
        int k = 0;
        while (true) {
            if (k + 1 < c) {
                #pragma unroll
                for (int j = 0; j < 8; ++j) uQ[j] = Xv[(size_t)idQ[j] * 64 + lane];
                if (k + 2 < c) {
                    #pragma unroll
                    for (int j = 0; j < 8; ++j) idP[j] = ed[(k + 2) * 8 + j];
                }
            }
            #pragma unroll
            for (int j = 0; j < 8; ++j) add8(acc, uP[j]);
            ++k;
            if (k >= c) break;
            if (k + 1 < c) {
                #pragma unroll
                for (int j = 0; j < 8; ++j) uP[j] = Xv[(size_t)idP[j] * 64 + lane];
                if (k + 2 < c) {
                    #pragma unroll
                    for (int j = 0; j < 8; ++j) idQ[j] = ed[(k + 2) * 8 + j];
                }
            }
            #pragma unroll
            for (int j = 0; j < 8; ++j) add8(acc, uQ[j]);
            ++k;
            if (k >= c) break;
        }
    }
    for (; i < n; ++i) add8(acc, Xv[(size_t)ed[i] * 64 + lane]);
    float sc = rsqrtf(fmaxf((float)n, 1.0f));
    uint4 o;
    o.x = (uint_t)f2b(acc[0] * sc) | ((uint_t)f2b(acc[1] * sc) << 16);
    o.y = (uint_t)f2b(acc[2] * sc) | ((uint_t)f2b(acc[3] * sc) << 16);
    o.z = (uint_t)f2b(acc[4] * sc) | ((uint_t)f2b(acc[5] * sc) << 16);
    o.w = (uint_t)f2b(acc[6] * sc) | ((uint_t)f2b(acc[7] * sc) << 16);
    ((uint4*)out)[(size_t)d * 64 + lane] = o;
}

// m97-style GEMM: C[M,N] = relu(A[M,K]bf16 @ BT[N,K]bf16^T + bias) (* rsqrt(rowCnt))
// 128x128 tile / 256 threads / BK=64; global_load_lds 16B staging; 32 MFMA per K-step/wave.
template <typename OutT>
__global__ __launch_bounds__(256) void gemm128(const ushort_t* __restrict__ A, const ushort_t* __restrict__ BT,
                                               const float* __restrict__ bias, const int* __restrict__ rowCnt,
                                               OutT* __restrict__ C, int M, int N, int K) {
    __shared__ __align__(16) ushort_t As[128 * 64];
    __shared__ __align__(16) ushort_t Bs[128 * 64];
    int tid = threadIdx.x;
    int lane = tid & 63, w = tid >> 6;
    int m16 = lane & 15, quad = lane >> 4;
    int wm = w & 1, wn = w >> 1;
    int bm = blockIdx.x * 128, bn = blockIdx.y * 128;
    f4v acc[4][4] = {};
    for (int k0 = 0; k0 < K; k0 += 64) {
        #pragma unroll
        for (int i = 0; i < 4; ++i) {
            int c = i * 256 + tid;          // chunk id: row = c>>3, 16B seg = c&7
            int row = c >> 3, seg = (c & 7) * 8;
            int ra = bm + row; if (ra >= M) ra = M - 1;
            __builtin_amdgcn_global_load_lds(
                (const __attribute__((address_space(1))) uint_t*)(A + (size_t)ra * K + k0 + seg),
                (__attribute__((address_space(3))) uint_t*)(As + (size_t)c * 8), 16, 0, 0);
        }
        #pragma unroll
        for (int i = 0; i < 4; ++i) {
            int c = i * 256 + tid;
            int row = c >> 3, seg = (c & 7) * 8;
            int rb = bn + row;              // N is a multiple of 128 here
            __builtin_amdgcn_global_load_lds(
                (const __attribute__((address_space(1))) uint_t*)(BT + (size_t)rb * K + k0 + seg),
                (__attribute__((address_space(3))) uint_t*)(Bs + (size_t)c * 8), 16, 0, 0);
        }
        __syncthreads();
        #pragma unroll
        for (int kc = 0; kc < 2; ++kc) {
            int co = kc * 32 + quad * 8;
            s8v af[4], bf[4];
            #pragma unroll
            for (int m = 0; m < 4; ++m)
                af[m] = *(const s8v*)&As[(wm * 64 + m * 16 + m16) * 64 + co];
            #pragma unroll
            for (int nn = 0; nn < 4; ++nn)
                bf[nn] = *(const s8v*)&Bs[(wn * 64 + nn * 16 + m16) * 64 + co];
            #pragma unroll
            for (int m = 0; m < 4; ++m)
                #pragma unroll
                for (int nn = 0; nn < 4; ++nn)
                    acc[m][nn] = __builtin_amdgcn_mfma_f32_16x16x32_bf16(af[m], bf[nn], acc[m][nn], 0, 0, 0);
        }
        __syncthreads();
    }
    #pragma unroll
    for (int m = 0; m < 4; ++m) {
        #pragma unroll
        for (int rr = 0; rr < 4; ++rr) {
            int row = bm + wm * 64 + m * 16 + quad * 4 + rr;
            if (row < M) {
                float rs = rowCnt ? rsqrtf(fmaxf((float)rowCnt[row], 1.0f)) : 1.0f;
                #pragma unroll
                for (int nn = 0; nn < 4; ++nn) {
                    int col = bn + wn * 64 + nn * 16 + m16;
                    float v = fmaxf(acc[m][nn][rr] + bias[col], 0.0f) * rs;
                    if (sizeof(OutT) == 2)
                        ((ushort_t*)C)[(size_t)row * N + col] = f2b(v);
                    else
                        ((float*)C)[(size_t)row * N + col] = v;
                }
            }
        }
    }
}

extern "C" void kernel_launch(void* const* d_in, const int* in_sizes, int n_in,
                              void* d_out, int out_size, void* d_ws, size_t ws_size,
                              hipStream_t stream) {
    (void)in_sizes; (void)n_in; (void)out_size; (void)ws_size;
    const float* x    = (const float*)d_in[0];
    const int*   src0 = (const int*)d_in[1];
    const int*   dst0 = (const int*)d_in[2];
    const int*   src1 = (const int*)d_in[3];
    const int*   dst1 = (const int*)d_in[4];
    const float* W1   = (const float*)d_in[5];
    const float* b1   = (const float*)d_in[6];
    const float* W2   = (const float*)d_in[7];
    const float* b2   = (const float*)d_in[8];
    float* out = (float*)d_out;

    char* p = (char*)d_ws;
    auto alloc = [&](size_t bytes) { char* q = p; p += (bytes + 255) & ~(size_t)255; return q; };
    int*      cnt  = (int*)alloc((size_t)NCNT * 4);
    int*      es0  = (int*)alloc((size_t)ND0 * SB * 4);
    int*      es1  = (int*)alloc((size_t)ND1 * SB * 4);
    ushort_t* wt1  = (ushort_t*)alloc((size_t)F * F * 2);
    ushort_t* wt2  = (ushort_t*)alloc((size_t)OF * F * 2);
    ushort_t* agg0 = (ushort_t*)alloc((size_t)ND0 * F * 2);
    ushort_t* h    = (ushort_t*)alloc((size_t)ND0 * F * 2);
    ushort_t* agg1 = (ushort_t*)alloc((size_t)ND1 * F * 2);

    int* cntOut0 = cnt;                      // [NS0]
    int* cntIn0  = cnt + NS0;                // [ND0]
    int* cntOut1 = cnt + NS0 + ND0;          // [ND0]
    int* cntIn1  = cnt + NS0 + ND0 + ND0;    // [ND1]

    (void)hipMemsetAsync(cnt, 0, (size_t)NCNT * 4, stream);

    prep<<<750 + WBLK, 256, 0, stream>>>(src0, dst0, src1, dst1,
                                         cntOut0, cntIn0, cntOut1, cntIn1, es0, es1,
                                         W1, W2, wt1, wt2);

    agg_l1<<<(ND0 + 3) / 4, 256, 0, stream>>>(x, es0, cntIn0, cntOut0, agg0, ND0);

    gemm128<ushort_t><<<dim3((ND0 + 127) / 128, F / 128), 256, 0, stream>>>(
        agg0, wt1, b1, cntOut1, h, ND0, F, F);

    agg_l2<<<(ND1 + 3) / 4, 256, 0, stream>>>(h, es1, cntIn1, agg1, ND1);

    gemm128<float><<<dim3((ND1 + 127) / 128, OF / 128), 256, 0, stream>>>(
        agg1, wt2, b2, nullptr, out, ND1, OF, F);
}